// Round 5
// baseline (527.373 us; speedup 1.0000x reference)
//
#include <hip/hip_runtime.h>

#define N_NODES 50000
#define N_EDGES 600000
#define IN_CH 64
#define HID 128
#define N_GRAPHS 64

// ---- bf16 helpers (manual, RNE) ----
__device__ __forceinline__ float bf2f(unsigned short u) {
    union { unsigned int i; float f; } v; v.i = ((unsigned int)u) << 16; return v.f;
}
__device__ __forceinline__ unsigned short f2bf(float f) {
    union { float f; unsigned int i; } v; v.f = f;
    unsigned int u = v.i;
    return (unsigned short)((u + 0x7FFFu + ((u >> 16) & 1u)) >> 16);
}

// ===========================================================================
// CSR build: counting-sort edges by dst. scatter packs a permuted per-edge
// record edata[pos] = {src, a0, a1, a2} (one 16B broadcast load per edge).
// ===========================================================================
__global__ void hist_kernel(const int* __restrict__ ei, int* __restrict__ deg) {
    int e = blockIdx.x * blockDim.x + threadIdx.x;
    if (e < N_EDGES) atomicAdd(&deg[ei[N_EDGES + e]], 1);
}

// Single-block scan, chunked: serial local sum -> 1024-wide LDS scan ->
// serial write-back. Replaces R4's 49-iteration x 2-sync version.
__global__ void scan_kernel(const int* __restrict__ deg,
                            int* __restrict__ rowptr,
                            int* __restrict__ cursor) {
    __shared__ int partial[1024];
    const int t = threadIdx.x;
    const int CHUNK = (N_NODES + 1023) / 1024;  // 49
    int begin = t * CHUNK;
    int end = begin + CHUNK; if (end > N_NODES) end = N_NODES;
    int sum = 0;
    for (int i = begin; i < end; i++) sum += deg[i];
    int val = sum;
    partial[t] = val;
    __syncthreads();
    for (int off = 1; off < 1024; off <<= 1) {
        int n = (t >= off) ? partial[t - off] : 0;
        __syncthreads();
        val += n;
        partial[t] = val;
        __syncthreads();
    }
    int run = val - sum;  // exclusive prefix of this chunk
    for (int i = begin; i < end; i++) { rowptr[i] = run; cursor[i] = run; run += deg[i]; }
    if (t == 1023) rowptr[N_NODES] = run;  // == N_EDGES
}

__global__ void scatter_kernel(const int* __restrict__ ei,
                               const float* __restrict__ ea,
                               int* __restrict__ cursor,
                               int4* __restrict__ edata) {
    int e = blockIdx.x * blockDim.x + threadIdx.x;
    if (e < N_EDGES) {
        int dst = ei[N_EDGES + e];
        int pos = atomicAdd(&cursor[dst], 1);
        edata[pos] = make_int4(ei[e],
                               __float_as_int(ea[3 * e]),
                               __float_as_int(ea[3 * e + 1]),
                               __float_as_int(ea[3 * e + 2]));
    }
}

// f32 -> bf16 conversion for the input features
__global__ void cvt_kernel(const float* __restrict__ in, unsigned short* __restrict__ out,
                           int n) {
    int i = blockIdx.x * blockDim.x + threadIdx.x;
    if (i < n) out[i] = f2bf(in[i]);
}

// ===========================================================================
// Fused GINE layer (bf16 node features in, f32 math):
//   sIn = x[n] + sum_{e: dst(e)=n} relu(x[src(e)] + ea[e]@elw + elb)
//   out = relu( relu(sIn@wa+ba) @ wb + bb )
// Edge loop unrolled x8 (+4 +1 tails): 8 bf16 row gathers in flight.
// POOL=false: write bf16 h.  POOL=true: f32 atomics into per-graph pool sums.
// ===========================================================================
template <int K, int NPB, bool POOL>
__global__ void fused_layer(const unsigned short* __restrict__ xin,  // bf16 [N,K]
                            const int4* __restrict__ edata,
                            const int* __restrict__ rowptr,
                            const float* __restrict__ elw,  // [3, K]
                            const float* __restrict__ elb,  // [K]
                            const float* __restrict__ wa,   // [K, HID]
                            const float* __restrict__ ba,
                            const float* __restrict__ wb,   // [HID, HID]
                            const float* __restrict__ bb,
                            void* __restrict__ outv,        // bf16 [N,HID] or f32 psum
                            const int* __restrict__ batch) {
    __shared__ float sIn[NPB][K];
    __shared__ float sHid[NPB][HID];
    const int node0 = blockIdx.x * NPB;
    const int t = threadIdx.x;  // 0..127

    // ---- aggregation (gather over CSR, 8 rows in flight) ----
    {
        const int c = (K == 128) ? t : (t & 63);
        const int half = (K == 128) ? 0 : (t >> 6);
        const int istep = (K == 128) ? 1 : 2;
        const float w0 = elw[c], w1 = elw[K + c], w2 = elw[2 * K + c], eb = elb[c];

        auto term = [&](int4 e, unsigned short row) -> float {
            float ev = __int_as_float(e.y) * w0 + __int_as_float(e.z) * w1 +
                       __int_as_float(e.w) * w2 + eb;
            float m = bf2f(row) + ev;
            return m > 0.f ? m : 0.f;
        };

        for (int i = 0; i < NPB; i += istep) {
            int node = node0 + i + half;
            float acc = bf2f(xin[(size_t)node * K + c]);
            int jb = rowptr[node], je = rowptr[node + 1];
            int j = jb;
            for (; j + 8 <= je; j += 8) {
                int4 e0 = edata[j],     e1 = edata[j + 1], e2 = edata[j + 2], e3 = edata[j + 3];
                int4 e4 = edata[j + 4], e5 = edata[j + 5], e6 = edata[j + 6], e7 = edata[j + 7];
                unsigned short r0 = xin[(size_t)e0.x * K + c];
                unsigned short r1 = xin[(size_t)e1.x * K + c];
                unsigned short r2 = xin[(size_t)e2.x * K + c];
                unsigned short r3 = xin[(size_t)e3.x * K + c];
                unsigned short r4 = xin[(size_t)e4.x * K + c];
                unsigned short r5 = xin[(size_t)e5.x * K + c];
                unsigned short r6 = xin[(size_t)e6.x * K + c];
                unsigned short r7 = xin[(size_t)e7.x * K + c];
                acc += term(e0, r0) + term(e1, r1) + term(e2, r2) + term(e3, r3)
                     + term(e4, r4) + term(e5, r5) + term(e6, r6) + term(e7, r7);
            }
            for (; j + 4 <= je; j += 4) {
                int4 e0 = edata[j], e1 = edata[j + 1], e2 = edata[j + 2], e3 = edata[j + 3];
                unsigned short r0 = xin[(size_t)e0.x * K + c];
                unsigned short r1 = xin[(size_t)e1.x * K + c];
                unsigned short r2 = xin[(size_t)e2.x * K + c];
                unsigned short r3 = xin[(size_t)e3.x * K + c];
                acc += term(e0, r0) + term(e1, r1) + term(e2, r2) + term(e3, r3);
            }
            for (; j < je; j++) {
                int4 e0 = edata[j];
                acc += term(e0, xin[(size_t)e0.x * K + c]);
            }
            sIn[i + half][c] = acc;
        }
    }
    __syncthreads();

    // ---- MLP layer A: sHid = relu(sIn @ wa + ba) ----
    float acc[NPB];
    #pragma unroll
    for (int i = 0; i < NPB; i++) acc[i] = ba[t];
    for (int k = 0; k < K; k++) {
        float w = wa[k * HID + t];
        #pragma unroll
        for (int i = 0; i < NPB; i++) acc[i] += sIn[i][k] * w;
    }
    #pragma unroll
    for (int i = 0; i < NPB; i++) sHid[i][t] = acc[i] > 0.f ? acc[i] : 0.f;
    __syncthreads();

    // ---- MLP layer B + outer relu ----
    float acc2[NPB];
    #pragma unroll
    for (int i = 0; i < NPB; i++) acc2[i] = bb[t];
    for (int k = 0; k < HID; k++) {
        float w = wb[k * HID + t];
        #pragma unroll
        for (int i = 0; i < NPB; i++) acc2[i] += sHid[i][k] * w;
    }
    #pragma unroll
    for (int i = 0; i < NPB; i++) {
        int node = node0 + i;
        float v = acc2[i] > 0.f ? acc2[i] : 0.f;
        if (POOL) {
            atomicAdd(&((float*)outv)[batch[node] * HID + t], v);
        } else {
            ((unsigned short*)outv)[(size_t)node * HID + t] = f2bf(v);
        }
    }
}

// ---------------------------------------------------------------------------
// Pool mean: batch is SORTED -> count[g] by binary search (wave-uniform).
// ---------------------------------------------------------------------------
__global__ void pool_div_kernel(const float* __restrict__ sums,
                                const int* __restrict__ batch,
                                float* __restrict__ out) {
    int i = blockIdx.x * blockDim.x + threadIdx.x;
    if (i >= N_GRAPHS * HID) return;
    int g = i / HID;
    int lo = 0, hi = N_NODES;
    while (lo < hi) { int mid = (lo + hi) >> 1; if (batch[mid] < g) lo = mid + 1; else hi = mid; }
    int start = lo;
    lo = 0; hi = N_NODES;
    while (lo < hi) { int mid = (lo + hi) >> 1; if (batch[mid] <= g) lo = mid + 1; else hi = mid; }
    float c = (float)(lo - start);
    out[i] = sums[i] / (c > 1.0f ? c : 1.0f);
}

extern "C" void kernel_launch(void* const* d_in, const int* in_sizes, int n_in,
                              void* d_out, int out_size, void* d_ws, size_t ws_size,
                              hipStream_t stream) {
    const float* x    = (const float*)d_in[0];
    const int*   ei   = (const int*)d_in[1];
    const float* ea   = (const float*)d_in[2];
    const int*   batch= (const int*)d_in[3];
    const float* el1w = (const float*)d_in[4];
    const float* el1b = (const float*)d_in[5];
    const float* w1a  = (const float*)d_in[6];
    const float* b1a  = (const float*)d_in[7];
    const float* w1b  = (const float*)d_in[8];
    const float* b1b  = (const float*)d_in[9];
    const float* el2w = (const float*)d_in[10];
    const float* el2b = (const float*)d_in[11];
    const float* w2a  = (const float*)d_in[12];
    const float* b2a  = (const float*)d_in[13];
    const float* w2b  = (const float*)d_in[14];
    const float* b2b  = (const float*)d_in[15];
    float* out = (float*)d_out;

    // workspace layout (edata first: 16B alignment)
    int4*           edata  = (int4*)d_ws;                       // [E] {src,a0,a1,a2}
    int*            deg    = (int*)(edata + N_EDGES);           // [N]
    int*            cursor = deg + N_NODES;                     // [N]
    int*            rowptr = cursor + N_NODES;                  // [N+1]
    float*          psum   = (float*)(rowptr + N_NODES + 2);    // [G, HID]
    unsigned short* xbf    = (unsigned short*)(psum + N_GRAPHS * HID);  // bf16 [N, IN_CH]
    unsigned short* hbf    = xbf + (size_t)N_NODES * IN_CH;     // bf16 [N, HID]

    // ---- CSR build + x conversion (independent of each other) ----
    hipMemsetAsync(deg, 0, N_NODES * sizeof(int), stream);
    hist_kernel<<<(N_EDGES + 255) / 256, 256, 0, stream>>>(ei, deg);
    cvt_kernel<<<(N_NODES * IN_CH + 255) / 256, 256, 0, stream>>>(x, xbf, N_NODES * IN_CH);
    scan_kernel<<<1, 1024, 0, stream>>>(deg, rowptr, cursor);
    scatter_kernel<<<(N_EDGES + 255) / 256, 256, 0, stream>>>(ei, ea, cursor, edata);

    // ---- layer 1 (gather + MLP fused, bf16 in, bf16 h out) ----
    fused_layer<IN_CH, 8, false><<<N_NODES / 8, 128, 0, stream>>>(
        xbf, edata, rowptr, el1w, el1b, w1a, b1a, w1b, b1b, hbf, nullptr);

    // ---- layer 2 (gather + MLP + pool fused) ----
    hipMemsetAsync(psum, 0, N_GRAPHS * HID * sizeof(float), stream);
    fused_layer<HID, 8, true><<<N_NODES / 8, 128, 0, stream>>>(
        hbf, edata, rowptr, el2w, el2b, w2a, b2a, w2b, b2b, psum, batch);

    // ---- mean (count via binary search on sorted batch) ----
    pool_div_kernel<<<(N_GRAPHS * HID + 255) / 256, 256, 0, stream>>>(psum, batch, out);
}